// Round 1
// 150.083 us; speedup vs baseline: 1.0111x; 1.0111x over previous
//
#include <hip/hip_runtime.h>
#include <hip/hip_bf16.h>

// CrossAttention: B=4, C=256, H=W=64 -> N=M=4096, RC=32
// v8: PV switched to MX-scaled mfma_scale_f32_32x32x64_f8f6f4 with unit
//     scales (e8m0=127): 2.26x fp8 MFMA rate, 8x fewer MFMA issues.
//     Wave iter-tile 64n x 64d x 64m = 2x2 tiles of 32x32x64.
//     V LDS reads: same 8 ds_read_b64 addresses as v7, regrouped per-lane.
//     P rows restrided 72->80 B so B-frags are two aligned ds_read_b128.
//     Epilogue rewritten for the 32x32 C layout.

#define B_ 4
#define C_ 256
#define N_ 4096
#define M_ 4096
#define SCALE_ 0.17677669529663687f  // 1/sqrt(32)

typedef __bf16 bf16x8 __attribute__((ext_vector_type(8)));
typedef float f32x4 __attribute__((ext_vector_type(4)));
typedef float f32x16 __attribute__((ext_vector_type(16)));
typedef int i32x8 __attribute__((ext_vector_type(8)));

#define AS1 __attribute__((address_space(1)))
#define AS3 __attribute__((address_space(3)))

static __device__ __forceinline__ unsigned short f2bf(float f) {
    unsigned int u = __float_as_uint(f);
    return (unsigned short)((u + 0x7fffu + ((u >> 16) & 1u)) >> 16);
}
static __device__ __forceinline__ unsigned bfpk(float a, float b) {
    return (unsigned)f2bf(a) | ((unsigned)f2bf(b) << 16);
}
static __device__ __forceinline__ float fp8d(unsigned v) {  // e4m3fn decode
    unsigned e = (v >> 3) & 15, m = v & 7;
    float f = e ? __uint_as_float(((e + 120u) << 23) | (m << 20))
                : (float)m * 0x1p-9f;
    return (v & 0x80u) ? -f : f;
}
static __device__ __forceinline__ void gload_lds16(const void* g, void* l) {
    __builtin_amdgcn_global_load_lds((const AS1 unsigned int*)g,
                                     (AS3 unsigned int*)l, 16, 0, 0);
}

// ---------------------------------------------------------------------------
// prep: weights -> bf16 MFMA fragment order. grid 40 x 256. (unchanged)
// ---------------------------------------------------------------------------
__global__ __launch_bounds__(256) void prep(
        const float* __restrict__ Wq, const float* __restrict__ Wk,
        const float* __restrict__ Wv, uint4* __restrict__ Wqf,
        uint4* __restrict__ Wkf, uint4* __restrict__ Wvf) {
    int bid = blockIdx.x, t = threadIdx.x;
    const float* W;
    uint4* dst;
    int frag;
    if (bid < 32)      { W = Wv; dst = Wvf; frag = (bid * 256 + t) >> 6; }
    else if (bid < 36) { W = Wq; dst = Wqf; frag = ((bid - 32) * 256 + t) >> 6; }
    else               { W = Wk; dst = Wkf; frag = ((bid - 36) * 256 + t) >> 6; }
    int lane = t & 63, low = lane & 15, q = lane >> 4;
    int fch = frag & 7, fr = frag >> 3;
    const float* wp = W + (size_t)(fr * 16 + low) * C_ + fch * 32 + q * 8;
    float4 w0 = *(const float4*)wp;
    float4 w1 = *(const float4*)(wp + 4);
    uint4 pk = {bfpk(w0.x, w0.y), bfpk(w0.z, w0.w),
                bfpk(w1.x, w1.y), bfpk(w1.z, w1.w)};
    dst[(size_t)frag * 64 + lane] = pk;
}

// ---------------------------------------------------------------------------
// Fused transpose + projections. grid 512 x 256. (unchanged from v6)
// ---------------------------------------------------------------------------
__global__ __launch_bounds__(256, 2) void fused_proj(
        const float* __restrict__ x, const float* __restrict__ ctx,
        const uint4* __restrict__ Wqf, const uint4* __restrict__ Wkf,
        const uint4* __restrict__ Wvf,
        const float* __restrict__ bq, const float* __restrict__ bk,
        const float* __restrict__ bv,
        unsigned short* __restrict__ Qf, unsigned short* __restrict__ Kf,
        unsigned char* __restrict__ Vf) {
    __shared__ unsigned short X[64][264];
    __shared__ unsigned short Pl[4][16 * 40];
    __shared__ unsigned char  Vw[4][16 * 40];

    int bid = blockIdx.x;
    bool isX = bid >= 256;
    int lb = bid & 255;
    int b = lb >> 6, pt64 = lb & 63;
    const float* __restrict__ in = (isX ? x : ctx) + (size_t)b * C_ * N_ + pt64 * 64;
    int t = threadIdx.x, wg = t >> 6, lane = t & 63;
    int low = lane & 15, q = lane >> 4;

    {
        int pL = lane;
        const float* s0 = in + pL;
#pragma unroll
        for (int ct = 0; ct < 4; ct++) {
            const float* s2 = s0 + (size_t)(ct * 64 + wg * 16) * N_;
            float v[16];
#pragma unroll
            for (int k = 0; k < 16; k++) v[k] = s2[(size_t)k * N_];
#pragma unroll
            for (int k = 0; k < 16; k += 2)
                *(unsigned*)&X[pL][ct * 64 + wg * 16 + k] = bfpk(v[k], v[k + 1]);
        }
    }
    __syncthreads();

    {
        const uint4* __restrict__ Wf = isX ? Wqf : Wkf;
        const float* __restrict__ bias = isX ? bq : bk;
        unsigned short* __restrict__ dst = isX ? Qf : Kf;
        bf16x8 xf[8];
#pragma unroll
        for (int ch = 0; ch < 8; ch++)
            xf[ch] = *(const bf16x8*)&X[wg * 16 + low][ch * 32 + q * 8];
        const f32x4 zero = {0.f, 0.f, 0.f, 0.f};
        f32x4 acc[2] = {zero, zero};
#pragma unroll
        for (int rt = 0; rt < 2; rt++)
#pragma unroll
            for (int ch = 0; ch < 8; ch++) {
                uint4 wv = Wf[(rt * 8 + ch) * 64 + lane];
                acc[rt] = __builtin_amdgcn_mfma_f32_16x16x32_bf16(
                    __builtin_bit_cast(bf16x8, wv), xf[ch], acc[rt], 0, 0, 0);
            }
        unsigned short* Pw = &Pl[wg][0];
#pragma unroll
        for (int rt = 0; rt < 2; rt++) {
            float b0 = bias[rt * 16 + q * 4 + 0], b1 = bias[rt * 16 + q * 4 + 1];
            float b2 = bias[rt * 16 + q * 4 + 2], b3 = bias[rt * 16 + q * 4 + 3];
            uint2 pk = {bfpk(acc[rt][0] + b0, acc[rt][1] + b1),
                        bfpk(acc[rt][2] + b2, acc[rt][3] + b3)};
            *(uint2*)(Pw + low * 40 + rt * 16 + q * 4) = pk;
        }
        uint4 frag = *(const uint4*)(Pw + low * 40 + q * 8);
        ((uint4*)dst)[((size_t)b * 256 + pt64 * 4 + wg) * 64 + lane] = frag;
    }

    if (!isX) {
        int mstep = wg >> 1, dh = wg & 1;
        bf16x8 vfr[2][8];
#pragma unroll
        for (int mt = 0; mt < 2; mt++)
#pragma unroll
            for (int ch = 0; ch < 8; ch++)
                vfr[mt][ch] = *(const bf16x8*)&X[mstep * 32 + mt * 16 + low][ch * 32 + q * 8];
        unsigned char* Vv = &Vw[wg][0];
        int msg = pt64 * 2 + mstep;
        const f32x4 zero = {0.f, 0.f, 0.f, 0.f};
#pragma unroll
        for (int dt8 = 0; dt8 < 8; dt8++) {
            int dt = dh * 8 + dt8;
            f32x4 a0 = zero, a1 = zero;
#pragma unroll
            for (int ch = 0; ch < 8; ch++) {
                uint4 wv = Wvf[(dt * 8 + ch) * 64 + lane];
                bf16x8 wfr = __builtin_bit_cast(bf16x8, wv);
                a0 = __builtin_amdgcn_mfma_f32_16x16x32_bf16(vfr[0][ch], wfr, a0, 0, 0, 0);
                a1 = __builtin_amdgcn_mfma_f32_16x16x32_bf16(vfr[1][ch], wfr, a1, 0, 0, 0);
            }
            float bb = bv[dt * 16 + low];
            unsigned w0 = __builtin_amdgcn_cvt_pk_fp8_f32(a0[0] + bb, a0[1] + bb, 0, false);
            w0 = __builtin_amdgcn_cvt_pk_fp8_f32(a0[2] + bb, a0[3] + bb, w0, true);
            unsigned w1 = __builtin_amdgcn_cvt_pk_fp8_f32(a1[0] + bb, a1[1] + bb, 0, false);
            w1 = __builtin_amdgcn_cvt_pk_fp8_f32(a1[2] + bb, a1[3] + bb, w1, true);
            *(unsigned*)(Vv + low * 40 + q * 4) = w0;
            *(unsigned*)(Vv + low * 40 + 16 + q * 4) = w1;
            uint2 fr = *(const uint2*)(Vv + low * 40 + q * 8);
            ((uint2*)Vf)[(((size_t)b * 128 + msg) * 16 + dt) * 64 + lane] = fr;
        }
    }
}

// ---------------------------------------------------------------------------
// Flash attention v8. grid 768 (= 3 blocks/CU), 256 thr (4 waves).
// bid = (b*3+chunk)*64 + ng. Block: 4 q-tiles (64 n), m-chunk of ~1400.
// Wave w: S^T/softmax for tile w; PV for ALL tiles restricted to d range
// [64w, 64w+64). PV now uses mfma_scale_f32_32x32x64_f8f6f4 (unit scales):
// wave iter-tile = 2x2 tiles of 32n x 32d x 64m. P (fp8, [n][m] rows of
// 80 B) shared via LDS ping-pong; V slabs (64 m, 16 KB) DMA double-buffered.
// ---------------------------------------------------------------------------
__global__ __launch_bounds__(256, 3) void attn(
        const unsigned short* __restrict__ Qf, const unsigned short* __restrict__ Kf,
        const unsigned char* __restrict__ Vf, unsigned char* __restrict__ Op,
        float* __restrict__ Lp) {
    __shared__ __align__(16) unsigned char vbuf[2][16384];    // 32 KB
    __shared__ __align__(16) unsigned char Pb[2][4][16 * 80]; // 10240 B

    int bid = blockIdx.x;
    int v = bid >> 6;                 // b*3 + chunk (0..11)
    int ng = bid & 63;
    int b = v / 3;
    int chunk = v - b * 3;
    int I  = (chunk == 0) ? 22 : 21;  // 22+21+21 = 64 slabs of 64 m
    int s0 = (chunk == 0) ? 0 : (chunk == 1 ? 22 : 43);

    int wave = threadIdx.x >> 6, lane = threadIdx.x & 63;
    int q = lane >> 4, low = lane & 15;
    int hi = lane >> 5;               // m-half selector for PV frags
    int dsel = q & 1;                 // tile-parity selector (n / d)
    int nt = ng * 4 + wave;           // wave's own q-tile (0..255)

    const uint4* Qp = (const uint4*)Qf;
    const uint4* Kp = (const uint4*)Kf + (size_t)b * 256 * 64;
    const unsigned char* Vp = Vf + (size_t)b * 1048576;

    bf16x8 qa = __builtin_bit_cast(bf16x8, Qp[(size_t)(b * 256 + nt) * 64 + lane]);

    f32x16 acc2[2][2];                // [n-pair tp][d-group dg]: O^T 32x32 tiles
#pragma unroll
    for (int tp = 0; tp < 2; tp++)
#pragma unroll
        for (int dg = 0; dg < 2; dg++) acc2[tp][dg] = (f32x16)(0.f);
    float lacc = 0.f;
    const f32x4 zero = {0.f, 0.f, 0.f, 0.f};

    // ---- prologue: S^T(0), P(0), DMA V(0), prefetch K(1) ----
    uint4 kv[4];
#pragma unroll
    for (int u = 0; u < 4; u++)
        kv[u] = Kp[(size_t)(s0 * 4 + u) * 64 + lane];
    f32x4 s[4];
#pragma unroll
    for (int u = 0; u < 4; u++)
        s[u] = __builtin_amdgcn_mfma_f32_16x16x32_bf16(
            __builtin_bit_cast(bf16x8, kv[u]), qa, zero, 0, 0, 0);
#pragma unroll
    for (int ii = 0; ii < 4; ii++) {
        int ck = wave * 4 + ii;
        gload_lds16(Vp + (size_t)s0 * 16384 + ck * 1024 + lane * 16,
                    &vbuf[0][0] + ck * 1024 + lane * 16);
    }
    if (I > 1) {
#pragma unroll
        for (int u = 0; u < 4; u++)
            kv[u] = Kp[(size_t)((s0 + 1) * 4 + u) * 64 + lane];
    }
    {
        unsigned char* Pw = &Pb[0][wave][0];
#pragma unroll
        for (int u = 0; u < 4; u++) {
            float p0 = __expf(s[u][0] * SCALE_), p1 = __expf(s[u][1] * SCALE_);
            float p2 = __expf(s[u][2] * SCALE_), p3 = __expf(s[u][3] * SCALE_);
            lacc += p0 + p1 + p2 + p3;
            unsigned w = __builtin_amdgcn_cvt_pk_fp8_f32(p0, p1, 0, false);
            w = __builtin_amdgcn_cvt_pk_fp8_f32(p2, p3, w, true);
            *(unsigned*)(Pw + low * 80 + u * 16 + q * 4) = w;
        }
    }
    __syncthreads();

    // ---- main loop ----
    for (int i = 0; i < I; i++) {
        int cur = i & 1, nxt = cur ^ 1;
        if (i + 1 < I) {
#pragma unroll
            for (int ii = 0; ii < 4; ii++) {
                int ck = wave * 4 + ii;
                gload_lds16(Vp + (size_t)(s0 + i + 1) * 16384 + ck * 1024 + lane * 16,
                            &vbuf[nxt][0] + ck * 1024 + lane * 16);
            }
#pragma unroll
            for (int u = 0; u < 4; u++)
                s[u] = __builtin_amdgcn_mfma_f32_16x16x32_bf16(
                    __builtin_bit_cast(bf16x8, kv[u]), qa, zero, 0, 0, 0);
            if (i + 2 < I) {
#pragma unroll
                for (int u = 0; u < 4; u++)
                    kv[u] = Kp[(size_t)((s0 + i + 2) * 4 + u) * 64 + lane];
            }
        }

        // ---- PV(i): O^T[2x2 of 32x32] += V^T P^T via scaled MFMA K=64 ----
        const unsigned char* vb = &vbuf[cur][0];
        const unsigned char* Pr = &Pb[cur][0][0];
        // A-frags (V^T): lane holds d = dg*32 + (lane&31), m = hi*32 + 0..31.
        // Same address set as v7's 8x ds_read_b64, regrouped per-lane.
        i32x8 vf[2];
#pragma unroll
        for (int dg = 0; dg < 2; dg++) {
            int dt = wave * 4 + dg * 2 + dsel;
            const unsigned char* vp = vb + hi * 8192 + dt * 512 + low * 8;
            long* dqw = (long*)&vf[dg];
#pragma unroll
            for (int ss = 0; ss < 4; ss++)
                dqw[ss] = *(const long*)(vp + ss * 128);
        }
#pragma unroll
        for (int tp = 0; tp < 2; tp++) {
            // B-frag (P^T): lane holds n = tp*32 + (lane&31), m = hi*32 + 0..31
            const unsigned char* pr = Pr + (tp * 2 + dsel) * 1280 + low * 80 + hi * 32;
            i32x8 pf;
            ((uint4*)&pf)[0] = *(const uint4*)pr;
            ((uint4*)&pf)[1] = *(const uint4*)(pr + 16);
#pragma unroll
            for (int dg = 0; dg < 2; dg++)
                acc2[tp][dg] = __builtin_amdgcn_mfma_scale_f32_32x32x64_f8f6f4(
                    vf[dg], pf, acc2[tp][dg], 0, 0, 0, 127, 0, 127);
        }

        if (i + 1 < I) {
            unsigned char* Pw = &Pb[nxt][wave][0];
#pragma unroll
            for (int u = 0; u < 4; u++) {
                float p0 = __expf(s[u][0] * SCALE_), p1 = __expf(s[u][1] * SCALE_);
                float p2 = __expf(s[u][2] * SCALE_), p3 = __expf(s[u][3] * SCALE_);
                lacc += p0 + p1 + p2 + p3;
                unsigned w = __builtin_amdgcn_cvt_pk_fp8_f32(p0, p1, 0, false);
                w = __builtin_amdgcn_cvt_pk_fp8_f32(p2, p3, w, true);
                *(unsigned*)(Pw + low * 80 + u * 16 + q * 4) = w;
            }
        }
        __syncthreads();
    }

    // ---- l: reduce across quads (m-partials), store per n ----
    lacc += __shfl_xor(lacc, 16, 64);
    lacc += __shfl_xor(lacc, 32, 64);
    if (lane < 16)
        Lp[(size_t)v * 4096 + nt * 16 + lane] = lacc;

    // ---- O^T -> [n][d] fp8 via LDS (once per block) ----
    // 32x32 C layout: col = lane&31 (n), row = (reg&3)+8*(reg>>2)+4*hi (d).
    unsigned* Odw = (unsigned*)&vbuf[0][0];  // 64 rows x 68 dwords (17.4 KB)
    int l31 = lane & 31;
#pragma unroll
    for (int tp = 0; tp < 2; tp++)
#pragma unroll
        for (int dg = 0; dg < 2; dg++)
#pragma unroll
            for (int k = 0; k < 4; k++) {
                unsigned w = __builtin_amdgcn_cvt_pk_fp8_f32(
                    acc2[tp][dg][4 * k + 0], acc2[tp][dg][4 * k + 1], 0, false);
                w = __builtin_amdgcn_cvt_pk_fp8_f32(
                    acc2[tp][dg][4 * k + 2], acc2[tp][dg][4 * k + 3], w, true);
                Odw[(tp * 32 + l31) * 68 + wave * 16 + dg * 8 + k * 2 + hi] = w;
            }
    __syncthreads();
    {
        int n = threadIdx.x >> 2, c4 = threadIdx.x & 3;
        size_t rb = ((size_t)v * 4096 + ng * 64 + n) * 256;
#pragma unroll
        for (int k = 0; k < 4; k++)
            *(uint4*)(Op + rb + c4 * 64 + k * 16) =
                *(const uint4*)&Odw[n * 68 + c4 * 16 + k * 4];
    }
}

// ---------------------------------------------------------------------------
// Combine: out = gamma * (sum_p O_p) / (sum_p l_p) + x.
// Op is [partial][n][d] fp8 -> LDS transpose to write out[d][n]. grid 512.
// ---------------------------------------------------------------------------
__global__ __launch_bounds__(256) void combine(
        const unsigned char* __restrict__ Op, const float* __restrict__ Lp,
        const float* __restrict__ x, const float* __restrict__ gamma,
        float* __restrict__ out) {
    __shared__ float W[32][260];
    int bid = blockIdx.x;
    int b = bid >> 7, n0 = (bid & 127) * 32;
    int t = threadIdx.x;
    float g = gamma[0];
    {
        int d4 = t & 63, nn = t >> 6;
#pragma unroll
        for (int rr = 0; rr < 8; rr++) {
            int n = rr * 4 + nn;
            float o0 = 0.f, o1 = 0.f, o2 = 0.f, o3 = 0.f, l = 0.f;
#pragma unroll
            for (int p = 0; p < 3; p++) {
                size_t base = (size_t)(b * 3 + p) * 4096 + n0 + n;
                unsigned pv = *(const unsigned*)(Op + base * 256 + d4 * 4);
                o0 += fp8d(pv & 255u); o1 += fp8d((pv >> 8) & 255u);
                o2 += fp8d((pv >> 16) & 255u); o3 += fp8d(pv >> 24);
                l += Lp[base];
            }
            float sc = g / l;
            f32x4 w = {o0 * sc, o1 * sc, o2 * sc, o3 * sc};
            *(f32x4*)&W[n][d4 * 4] = w;
        }
    }
    __syncthreads();
    {
        int d = t;
        size_t rb = ((size_t)b * 256 + d) * 4096 + n0;
#pragma unroll
        for (int k = 0; k < 8; k++) {
            f32x4 xv = *(const f32x4*)(x + rb + k * 4);
            f32x4 res;
#pragma unroll
            for (int r = 0; r < 4; r++) res[r] = W[k * 4 + r][d] + xv[r];
            *(f32x4*)(out + rb + k * 4) = res;
        }
    }
}

// ---------------------------------------------------------------------------
extern "C" void kernel_launch(void* const* d_in, const int* in_sizes, int n_in,
                              void* d_out, int out_size, void* d_ws, size_t ws_size,
                              hipStream_t stream) {
    const float* x     = (const float*)d_in[0];
    const float* ctx   = (const float*)d_in[1];
    const float* Wq    = (const float*)d_in[2];
    const float* bq    = (const float*)d_in[3];
    const float* Wk    = (const float*)d_in[4];
    const float* bk    = (const float*)d_in[5];
    const float* Wv    = (const float*)d_in[6];
    const float* bv    = (const float*)d_in[7];
    const float* gamma = (const float*)d_in[8];
    float* out = (float*)d_out;

    // ws: Qf 1M | Kf 1M | Vf 4.2M | Wqf/Wkf 16K | Wvf 128K | Op 12.6M | Lp 196K
    unsigned short* Qf = (unsigned short*)d_ws;
    unsigned short* Kf = Qf + (size_t)B_ * N_ * 32;
    unsigned char*  Vf = (unsigned char*)(Kf + (size_t)B_ * M_ * 32);
    uint4* Wqf = (uint4*)(Vf + (size_t)B_ * M_ * C_);
    uint4* Wkf = Wqf + 16 * 64;
    uint4* Wvf = Wkf + 16 * 64;
    unsigned char* Op = (unsigned char*)(Wvf + 128 * 64);
    float* Lp = (float*)(Op + (size_t)3 * B_ * N_ * C_);

    prep<<<40, 256, 0, stream>>>(Wq, Wk, Wv, Wqf, Wkf, Wvf);
    fused_proj<<<512, 256, 0, stream>>>(x, ctx, Wqf, Wkf, Wvf, bq, bk, bv, Qf, Kf, Vf);
    attn<<<768, 256, 0, stream>>>(Qf, Kf, Vf, Op, Lp);
    combine<<<512, 256, 0, stream>>>(Op, Lp, x, gamma, out);
}

// Round 2
// 150.057 us; speedup vs baseline: 1.0113x; 1.0002x over previous
//
#include <hip/hip_runtime.h>
#include <hip/hip_bf16.h>

// CrossAttention: B=4, C=256, H=W=64 -> N=M=4096, RC=32
// v9: V operands loaded global->VGPR directly (Vf is already in fragment
//     order; no cross-wave V sharing). Removes the 16 KB/iter LDS DMA and
//     its vmcnt(0) drain at every barrier; LDS traffic per CU*iter drops
//     ~156 KB -> ~60 KB (P ping-pong only). vbuf eliminated; epilogue
//     transpose uses a dedicated 17 KB scratch. s_setprio(1) around PV.

#define B_ 4
#define C_ 256
#define N_ 4096
#define M_ 4096
#define SCALE_ 0.17677669529663687f  // 1/sqrt(32)

typedef __bf16 bf16x8 __attribute__((ext_vector_type(8)));
typedef float f32x4 __attribute__((ext_vector_type(4)));
typedef float f32x16 __attribute__((ext_vector_type(16)));
typedef int i32x8 __attribute__((ext_vector_type(8)));

#define AS1 __attribute__((address_space(1)))
#define AS3 __attribute__((address_space(3)))

static __device__ __forceinline__ unsigned short f2bf(float f) {
    unsigned int u = __float_as_uint(f);
    return (unsigned short)((u + 0x7fffu + ((u >> 16) & 1u)) >> 16);
}
static __device__ __forceinline__ unsigned bfpk(float a, float b) {
    return (unsigned)f2bf(a) | ((unsigned)f2bf(b) << 16);
}
static __device__ __forceinline__ float fp8d(unsigned v) {  // e4m3fn decode
    unsigned e = (v >> 3) & 15, m = v & 7;
    float f = e ? __uint_as_float(((e + 120u) << 23) | (m << 20))
                : (float)m * 0x1p-9f;
    return (v & 0x80u) ? -f : f;
}

// ---------------------------------------------------------------------------
// prep: weights -> bf16 MFMA fragment order. grid 40 x 256. (unchanged)
// ---------------------------------------------------------------------------
__global__ __launch_bounds__(256) void prep(
        const float* __restrict__ Wq, const float* __restrict__ Wk,
        const float* __restrict__ Wv, uint4* __restrict__ Wqf,
        uint4* __restrict__ Wkf, uint4* __restrict__ Wvf) {
    int bid = blockIdx.x, t = threadIdx.x;
    const float* W;
    uint4* dst;
    int frag;
    if (bid < 32)      { W = Wv; dst = Wvf; frag = (bid * 256 + t) >> 6; }
    else if (bid < 36) { W = Wq; dst = Wqf; frag = ((bid - 32) * 256 + t) >> 6; }
    else               { W = Wk; dst = Wkf; frag = ((bid - 36) * 256 + t) >> 6; }
    int lane = t & 63, low = lane & 15, q = lane >> 4;
    int fch = frag & 7, fr = frag >> 3;
    const float* wp = W + (size_t)(fr * 16 + low) * C_ + fch * 32 + q * 8;
    float4 w0 = *(const float4*)wp;
    float4 w1 = *(const float4*)(wp + 4);
    uint4 pk = {bfpk(w0.x, w0.y), bfpk(w0.z, w0.w),
                bfpk(w1.x, w1.y), bfpk(w1.z, w1.w)};
    dst[(size_t)frag * 64 + lane] = pk;
}

// ---------------------------------------------------------------------------
// Fused transpose + projections. grid 512 x 256. (unchanged from v6)
// ---------------------------------------------------------------------------
__global__ __launch_bounds__(256, 2) void fused_proj(
        const float* __restrict__ x, const float* __restrict__ ctx,
        const uint4* __restrict__ Wqf, const uint4* __restrict__ Wkf,
        const uint4* __restrict__ Wvf,
        const float* __restrict__ bq, const float* __restrict__ bk,
        const float* __restrict__ bv,
        unsigned short* __restrict__ Qf, unsigned short* __restrict__ Kf,
        unsigned char* __restrict__ Vf) {
    __shared__ unsigned short X[64][264];
    __shared__ unsigned short Pl[4][16 * 40];
    __shared__ unsigned char  Vw[4][16 * 40];

    int bid = blockIdx.x;
    bool isX = bid >= 256;
    int lb = bid & 255;
    int b = lb >> 6, pt64 = lb & 63;
    const float* __restrict__ in = (isX ? x : ctx) + (size_t)b * C_ * N_ + pt64 * 64;
    int t = threadIdx.x, wg = t >> 6, lane = t & 63;
    int low = lane & 15, q = lane >> 4;

    {
        int pL = lane;
        const float* s0 = in + pL;
#pragma unroll
        for (int ct = 0; ct < 4; ct++) {
            const float* s2 = s0 + (size_t)(ct * 64 + wg * 16) * N_;
            float v[16];
#pragma unroll
            for (int k = 0; k < 16; k++) v[k] = s2[(size_t)k * N_];
#pragma unroll
            for (int k = 0; k < 16; k += 2)
                *(unsigned*)&X[pL][ct * 64 + wg * 16 + k] = bfpk(v[k], v[k + 1]);
        }
    }
    __syncthreads();

    {
        const uint4* __restrict__ Wf = isX ? Wqf : Wkf;
        const float* __restrict__ bias = isX ? bq : bk;
        unsigned short* __restrict__ dst = isX ? Qf : Kf;
        bf16x8 xf[8];
#pragma unroll
        for (int ch = 0; ch < 8; ch++)
            xf[ch] = *(const bf16x8*)&X[wg * 16 + low][ch * 32 + q * 8];
        const f32x4 zero = {0.f, 0.f, 0.f, 0.f};
        f32x4 acc[2] = {zero, zero};
#pragma unroll
        for (int rt = 0; rt < 2; rt++)
#pragma unroll
            for (int ch = 0; ch < 8; ch++) {
                uint4 wv = Wf[(rt * 8 + ch) * 64 + lane];
                acc[rt] = __builtin_amdgcn_mfma_f32_16x16x32_bf16(
                    __builtin_bit_cast(bf16x8, wv), xf[ch], acc[rt], 0, 0, 0);
            }
        unsigned short* Pw = &Pl[wg][0];
#pragma unroll
        for (int rt = 0; rt < 2; rt++) {
            float b0 = bias[rt * 16 + q * 4 + 0], b1 = bias[rt * 16 + q * 4 + 1];
            float b2 = bias[rt * 16 + q * 4 + 2], b3 = bias[rt * 16 + q * 4 + 3];
            uint2 pk = {bfpk(acc[rt][0] + b0, acc[rt][1] + b1),
                        bfpk(acc[rt][2] + b2, acc[rt][3] + b3)};
            *(uint2*)(Pw + low * 40 + rt * 16 + q * 4) = pk;
        }
        uint4 frag = *(const uint4*)(Pw + low * 40 + q * 8);
        ((uint4*)dst)[((size_t)b * 256 + pt64 * 4 + wg) * 64 + lane] = frag;
    }

    if (!isX) {
        int mstep = wg >> 1, dh = wg & 1;
        bf16x8 vfr[2][8];
#pragma unroll
        for (int mt = 0; mt < 2; mt++)
#pragma unroll
            for (int ch = 0; ch < 8; ch++)
                vfr[mt][ch] = *(const bf16x8*)&X[mstep * 32 + mt * 16 + low][ch * 32 + q * 8];
        unsigned char* Vv = &Vw[wg][0];
        int msg = pt64 * 2 + mstep;
        const f32x4 zero = {0.f, 0.f, 0.f, 0.f};
#pragma unroll
        for (int dt8 = 0; dt8 < 8; dt8++) {
            int dt = dh * 8 + dt8;
            f32x4 a0 = zero, a1 = zero;
#pragma unroll
            for (int ch = 0; ch < 8; ch++) {
                uint4 wv = Wvf[(dt * 8 + ch) * 64 + lane];
                bf16x8 wfr = __builtin_bit_cast(bf16x8, wv);
                a0 = __builtin_amdgcn_mfma_f32_16x16x32_bf16(vfr[0][ch], wfr, a0, 0, 0, 0);
                a1 = __builtin_amdgcn_mfma_f32_16x16x32_bf16(vfr[1][ch], wfr, a1, 0, 0, 0);
            }
            float bb = bv[dt * 16 + low];
            unsigned w0 = __builtin_amdgcn_cvt_pk_fp8_f32(a0[0] + bb, a0[1] + bb, 0, false);
            w0 = __builtin_amdgcn_cvt_pk_fp8_f32(a0[2] + bb, a0[3] + bb, w0, true);
            unsigned w1 = __builtin_amdgcn_cvt_pk_fp8_f32(a1[0] + bb, a1[1] + bb, 0, false);
            w1 = __builtin_amdgcn_cvt_pk_fp8_f32(a1[2] + bb, a1[3] + bb, w1, true);
            *(unsigned*)(Vv + low * 40 + q * 4) = w0;
            *(unsigned*)(Vv + low * 40 + 16 + q * 4) = w1;
            uint2 fr = *(const uint2*)(Vv + low * 40 + q * 8);
            ((uint2*)Vf)[(((size_t)b * 128 + msg) * 16 + dt) * 64 + lane] = fr;
        }
    }
}

// ---------------------------------------------------------------------------
// Flash attention v9. grid 768 (= 3 blocks/CU), 256 thr (4 waves).
// bid = (b*3+chunk)*64 + ng. Block: 4 q-tiles (64 n), m-chunk of ~1400.
// Wave w: S^T/softmax for tile w; PV for ALL tiles restricted to d range
// [64w, 64w+64) using mfma_scale_f32_32x32x64_f8f6f4 (unit scales).
// V fragments load global->VGPR directly (L2-broadcast across the 64 ng
// blocks); LDS holds only the P ping-pong (10.25 KB) + epilogue scratch.
// ---------------------------------------------------------------------------
__global__ __launch_bounds__(256, 3) void attn(
        const unsigned short* __restrict__ Qf, const unsigned short* __restrict__ Kf,
        const unsigned char* __restrict__ Vf, unsigned char* __restrict__ Op,
        float* __restrict__ Lp) {
    __shared__ __align__(16) unsigned char Pb[2][4][16 * 80];  // 10240 B
    __shared__ __align__(16) unsigned Odw[64 * 68];            // 17408 B

    int bid = blockIdx.x;
    int v = bid >> 6;                 // b*3 + chunk (0..11)
    int ng = bid & 63;
    int b = v / 3;
    int chunk = v - b * 3;
    int I  = (chunk == 0) ? 22 : 21;  // 22+21+21 = 64 slabs of 64 m
    int s0 = (chunk == 0) ? 0 : (chunk == 1 ? 22 : 43);

    int wave = threadIdx.x >> 6, lane = threadIdx.x & 63;
    int q = lane >> 4, low = lane & 15;
    int hi = lane >> 5;               // m-half selector for PV frags
    int dsel = q & 1;                 // tile-parity selector (n / d)
    int nt = ng * 4 + wave;           // wave's own q-tile (0..255)

    const uint4* Qp = (const uint4*)Qf;
    const uint4* Kp = (const uint4*)Kf + (size_t)b * 256 * 64;
    // V fragment stream: uint2 index ((s0+i)*2 + hi)*1024 + dt*64 + ss*16 + low
    const uint2* Vq = (const uint2*)(Vf + (size_t)b * 1048576) + (size_t)hi * 1024 + low;

    bf16x8 qa = __builtin_bit_cast(bf16x8, Qp[(size_t)(b * 256 + nt) * 64 + lane]);

    f32x16 acc2[2][2];                // [n-pair tp][d-group dg]: O^T 32x32 tiles
#pragma unroll
    for (int tp = 0; tp < 2; tp++)
#pragma unroll
        for (int dg = 0; dg < 2; dg++) acc2[tp][dg] = (f32x16)(0.f);
    float lacc = 0.f;
    const f32x4 zero = {0.f, 0.f, 0.f, 0.f};

    // ---- prologue: S^T(0), P(0), prefetch K(1) ----
    uint4 kv[4];
#pragma unroll
    for (int u = 0; u < 4; u++)
        kv[u] = Kp[(size_t)(s0 * 4 + u) * 64 + lane];
    f32x4 s[4];
#pragma unroll
    for (int u = 0; u < 4; u++)
        s[u] = __builtin_amdgcn_mfma_f32_16x16x32_bf16(
            __builtin_bit_cast(bf16x8, kv[u]), qa, zero, 0, 0, 0);
    if (I > 1) {
#pragma unroll
        for (int u = 0; u < 4; u++)
            kv[u] = Kp[(size_t)((s0 + 1) * 4 + u) * 64 + lane];
    }
    {
        unsigned char* Pw = &Pb[0][wave][0];
#pragma unroll
        for (int u = 0; u < 4; u++) {
            float p0 = __expf(s[u][0] * SCALE_), p1 = __expf(s[u][1] * SCALE_);
            float p2 = __expf(s[u][2] * SCALE_), p3 = __expf(s[u][3] * SCALE_);
            lacc += p0 + p1 + p2 + p3;
            unsigned w = __builtin_amdgcn_cvt_pk_fp8_f32(p0, p1, 0, false);
            w = __builtin_amdgcn_cvt_pk_fp8_f32(p2, p3, w, true);
            *(unsigned*)(Pw + low * 80 + u * 16 + q * 4) = w;
        }
    }
    __syncthreads();

    // ---- main loop ----
    for (int i = 0; i < I; i++) {
        int cur = i & 1, nxt = cur ^ 1;

        // V(i) fragments: global -> VGPR (issued first; latency hidden by
        // QK^T issue + K prefetch + cross-wave interleave).
        i32x8 vf[2];
        {
            const uint2* Vs = Vq + (size_t)(s0 + i) * 2048;
#pragma unroll
            for (int dg = 0; dg < 2; dg++) {
                int dt = wave * 4 + dg * 2 + dsel;
                long* dqw = (long*)&vf[dg];
#pragma unroll
                for (int ss = 0; ss < 4; ss++)
                    dqw[ss] = *(const long*)(Vs + dt * 64 + ss * 16);
            }
        }

        if (i + 1 < I) {
#pragma unroll
            for (int u = 0; u < 4; u++)
                s[u] = __builtin_amdgcn_mfma_f32_16x16x32_bf16(
                    __builtin_bit_cast(bf16x8, kv[u]), qa, zero, 0, 0, 0);
            if (i + 2 < I) {
#pragma unroll
                for (int u = 0; u < 4; u++)
                    kv[u] = Kp[(size_t)((s0 + i + 2) * 4 + u) * 64 + lane];
            }
        }

        // ---- PV(i): O^T[2x2 of 32x32] += V^T P^T via scaled MFMA K=64 ----
        const unsigned char* Pr = &Pb[cur][0][0];
        __builtin_amdgcn_s_setprio(1);
#pragma unroll
        for (int tp = 0; tp < 2; tp++) {
            // B-frag (P^T): lane holds n = tp*32 + (lane&31), m = hi*32 + 0..31
            const unsigned char* pr = Pr + (tp * 2 + dsel) * 1280 + low * 80 + hi * 32;
            i32x8 pf;
            ((uint4*)&pf)[0] = *(const uint4*)pr;
            ((uint4*)&pf)[1] = *(const uint4*)(pr + 16);
#pragma unroll
            for (int dg = 0; dg < 2; dg++)
                acc2[tp][dg] = __builtin_amdgcn_mfma_scale_f32_32x32x64_f8f6f4(
                    vf[dg], pf, acc2[tp][dg], 0, 0, 0, 127, 0, 127);
        }
        __builtin_amdgcn_s_setprio(0);

        if (i + 1 < I) {
            unsigned char* Pw = &Pb[nxt][wave][0];
#pragma unroll
            for (int u = 0; u < 4; u++) {
                float p0 = __expf(s[u][0] * SCALE_), p1 = __expf(s[u][1] * SCALE_);
                float p2 = __expf(s[u][2] * SCALE_), p3 = __expf(s[u][3] * SCALE_);
                lacc += p0 + p1 + p2 + p3;
                unsigned w = __builtin_amdgcn_cvt_pk_fp8_f32(p0, p1, 0, false);
                w = __builtin_amdgcn_cvt_pk_fp8_f32(p2, p3, w, true);
                *(unsigned*)(Pw + low * 80 + u * 16 + q * 4) = w;
            }
        }
        __syncthreads();
    }

    // ---- l: reduce across quads (m-partials), store per n ----
    lacc += __shfl_xor(lacc, 16, 64);
    lacc += __shfl_xor(lacc, 32, 64);
    if (lane < 16)
        Lp[(size_t)v * 4096 + nt * 16 + lane] = lacc;

    // ---- O^T -> [n][d] fp8 via LDS (once per block) ----
    // 32x32 C layout: col = lane&31 (n), row = (reg&3)+8*(reg>>2)+4*hi (d).
    int l31 = lane & 31;
#pragma unroll
    for (int tp = 0; tp < 2; tp++)
#pragma unroll
        for (int dg = 0; dg < 2; dg++)
#pragma unroll
            for (int k = 0; k < 4; k++) {
                unsigned w = __builtin_amdgcn_cvt_pk_fp8_f32(
                    acc2[tp][dg][4 * k + 0], acc2[tp][dg][4 * k + 1], 0, false);
                w = __builtin_amdgcn_cvt_pk_fp8_f32(
                    acc2[tp][dg][4 * k + 2], acc2[tp][dg][4 * k + 3], w, true);
                Odw[(tp * 32 + l31) * 68 + wave * 16 + dg * 8 + k * 2 + hi] = w;
            }
    __syncthreads();
    {
        int n = threadIdx.x >> 2, c4 = threadIdx.x & 3;
        size_t rb = ((size_t)v * 4096 + ng * 64 + n) * 256;
#pragma unroll
        for (int k = 0; k < 4; k++)
            *(uint4*)(Op + rb + c4 * 64 + k * 16) =
                *(const uint4*)&Odw[n * 68 + c4 * 16 + k * 4];
    }
}

// ---------------------------------------------------------------------------
// Combine: out = gamma * (sum_p O_p) / (sum_p l_p) + x.
// Op is [partial][n][d] fp8 -> LDS transpose to write out[d][n]. grid 512.
// ---------------------------------------------------------------------------
__global__ __launch_bounds__(256) void combine(
        const unsigned char* __restrict__ Op, const float* __restrict__ Lp,
        const float* __restrict__ x, const float* __restrict__ gamma,
        float* __restrict__ out) {
    __shared__ float W[32][260];
    int bid = blockIdx.x;
    int b = bid >> 7, n0 = (bid & 127) * 32;
    int t = threadIdx.x;
    float g = gamma[0];
    {
        int d4 = t & 63, nn = t >> 6;
#pragma unroll
        for (int rr = 0; rr < 8; rr++) {
            int n = rr * 4 + nn;
            float o0 = 0.f, o1 = 0.f, o2 = 0.f, o3 = 0.f, l = 0.f;
#pragma unroll
            for (int p = 0; p < 3; p++) {
                size_t base = (size_t)(b * 3 + p) * 4096 + n0 + n;
                unsigned pv = *(const unsigned*)(Op + base * 256 + d4 * 4);
                o0 += fp8d(pv & 255u); o1 += fp8d((pv >> 8) & 255u);
                o2 += fp8d((pv >> 16) & 255u); o3 += fp8d(pv >> 24);
                l += Lp[base];
            }
            float sc = g / l;
            f32x4 w = {o0 * sc, o1 * sc, o2 * sc, o3 * sc};
            *(f32x4*)&W[n][d4 * 4] = w;
        }
    }
    __syncthreads();
    {
        int d = t;
        size_t rb = ((size_t)b * 256 + d) * 4096 + n0;
#pragma unroll
        for (int k = 0; k < 8; k++) {
            f32x4 xv = *(const f32x4*)(x + rb + k * 4);
            f32x4 res;
#pragma unroll
            for (int r = 0; r < 4; r++) res[r] = W[k * 4 + r][d] + xv[r];
            *(f32x4*)(out + rb + k * 4) = res;
        }
    }
}

// ---------------------------------------------------------------------------
extern "C" void kernel_launch(void* const* d_in, const int* in_sizes, int n_in,
                              void* d_out, int out_size, void* d_ws, size_t ws_size,
                              hipStream_t stream) {
    const float* x     = (const float*)d_in[0];
    const float* ctx   = (const float*)d_in[1];
    const float* Wq    = (const float*)d_in[2];
    const float* bq    = (const float*)d_in[3];
    const float* Wk    = (const float*)d_in[4];
    const float* bk    = (const float*)d_in[5];
    const float* Wv    = (const float*)d_in[6];
    const float* bv    = (const float*)d_in[7];
    const float* gamma = (const float*)d_in[8];
    float* out = (float*)d_out;

    // ws: Qf 1M | Kf 1M | Vf 4.2M | Wqf/Wkf 16K | Wvf 128K | Op 12.6M | Lp 196K
    unsigned short* Qf = (unsigned short*)d_ws;
    unsigned short* Kf = Qf + (size_t)B_ * N_ * 32;
    unsigned char*  Vf = (unsigned char*)(Kf + (size_t)B_ * M_ * 32);
    uint4* Wqf = (uint4*)(Vf + (size_t)B_ * M_ * C_);
    uint4* Wkf = Wqf + 16 * 64;
    uint4* Wvf = Wkf + 16 * 64;
    unsigned char* Op = (unsigned char*)(Wvf + 128 * 64);
    float* Lp = (float*)(Op + (size_t)3 * B_ * N_ * C_);

    prep<<<40, 256, 0, stream>>>(Wq, Wk, Wv, Wqf, Wkf, Wvf);
    fused_proj<<<512, 256, 0, stream>>>(x, ctx, Wqf, Wkf, Wvf, bq, bk, bv, Qf, Kf, Vf);
    attn<<<768, 256, 0, stream>>>(Qf, Kf, Vf, Op, Lp);
    combine<<<512, 256, 0, stream>>>(Op, Lp, x, gamma, out);
}

// Round 3
// 139.611 us; speedup vs baseline: 1.0870x; 1.0748x over previous
//
#include <hip/hip_runtime.h>
#include <hip/hip_bf16.h>

// CrossAttention: B=4, C=256, H=W=64 -> N=M=4096, RC=32
// v10: combine kernel ELIMINATED. attn blocks now cover the full m range
//      (grid 256 = 1 block/CU, 8 waves): waves 0-3 do QK^T/softmax/P-pack
//      (as before), all 8 waves do PV with d split 8 ways (32 d/wave,
//      scaled MFMA 32x32x64). Epilogue normalizes (l via LDS), transposes
//      O through a conflict-free bf16 LDS buffer and writes gamma*O/l + x
//      directly. Saves the Op/Lp 25 MB roundtrip + a launch. Bijective
//      bid swizzle keeps each b's K/V L2-resident on one XCD pair.

#define B_ 4
#define C_ 256
#define N_ 4096
#define M_ 4096
#define SCALE_ 0.17677669529663687f  // 1/sqrt(32)

typedef __bf16 bf16x8 __attribute__((ext_vector_type(8)));
typedef float f32x4 __attribute__((ext_vector_type(4)));
typedef float f32x16 __attribute__((ext_vector_type(16)));
typedef int i32x8 __attribute__((ext_vector_type(8)));

#define AS1 __attribute__((address_space(1)))
#define AS3 __attribute__((address_space(3)))

static __device__ __forceinline__ unsigned short f2bf(float f) {
    unsigned int u = __float_as_uint(f);
    return (unsigned short)((u + 0x7fffu + ((u >> 16) & 1u)) >> 16);
}
static __device__ __forceinline__ unsigned bfpk(float a, float b) {
    return (unsigned)f2bf(a) | ((unsigned)f2bf(b) << 16);
}

// ---------------------------------------------------------------------------
// prep: weights -> bf16 MFMA fragment order. grid 40 x 256. (unchanged)
// ---------------------------------------------------------------------------
__global__ __launch_bounds__(256) void prep(
        const float* __restrict__ Wq, const float* __restrict__ Wk,
        const float* __restrict__ Wv, uint4* __restrict__ Wqf,
        uint4* __restrict__ Wkf, uint4* __restrict__ Wvf) {
    int bid = blockIdx.x, t = threadIdx.x;
    const float* W;
    uint4* dst;
    int frag;
    if (bid < 32)      { W = Wv; dst = Wvf; frag = (bid * 256 + t) >> 6; }
    else if (bid < 36) { W = Wq; dst = Wqf; frag = ((bid - 32) * 256 + t) >> 6; }
    else               { W = Wk; dst = Wkf; frag = ((bid - 36) * 256 + t) >> 6; }
    int lane = t & 63, low = lane & 15, q = lane >> 4;
    int fch = frag & 7, fr = frag >> 3;
    const float* wp = W + (size_t)(fr * 16 + low) * C_ + fch * 32 + q * 8;
    float4 w0 = *(const float4*)wp;
    float4 w1 = *(const float4*)(wp + 4);
    uint4 pk = {bfpk(w0.x, w0.y), bfpk(w0.z, w0.w),
                bfpk(w1.x, w1.y), bfpk(w1.z, w1.w)};
    dst[(size_t)frag * 64 + lane] = pk;
}

// ---------------------------------------------------------------------------
// Fused transpose + projections. grid 512 x 256. (unchanged from v6)
// ---------------------------------------------------------------------------
__global__ __launch_bounds__(256, 2) void fused_proj(
        const float* __restrict__ x, const float* __restrict__ ctx,
        const uint4* __restrict__ Wqf, const uint4* __restrict__ Wkf,
        const uint4* __restrict__ Wvf,
        const float* __restrict__ bq, const float* __restrict__ bk,
        const float* __restrict__ bv,
        unsigned short* __restrict__ Qf, unsigned short* __restrict__ Kf,
        unsigned char* __restrict__ Vf) {
    __shared__ unsigned short X[64][264];
    __shared__ unsigned short Pl[4][16 * 40];
    __shared__ unsigned char  Vw[4][16 * 40];

    int bid = blockIdx.x;
    bool isX = bid >= 256;
    int lb = bid & 255;
    int b = lb >> 6, pt64 = lb & 63;
    const float* __restrict__ in = (isX ? x : ctx) + (size_t)b * C_ * N_ + pt64 * 64;
    int t = threadIdx.x, wg = t >> 6, lane = t & 63;
    int low = lane & 15, q = lane >> 4;

    {
        int pL = lane;
        const float* s0 = in + pL;
#pragma unroll
        for (int ct = 0; ct < 4; ct++) {
            const float* s2 = s0 + (size_t)(ct * 64 + wg * 16) * N_;
            float v[16];
#pragma unroll
            for (int k = 0; k < 16; k++) v[k] = s2[(size_t)k * N_];
#pragma unroll
            for (int k = 0; k < 16; k += 2)
                *(unsigned*)&X[pL][ct * 64 + wg * 16 + k] = bfpk(v[k], v[k + 1]);
        }
    }
    __syncthreads();

    {
        const uint4* __restrict__ Wf = isX ? Wqf : Wkf;
        const float* __restrict__ bias = isX ? bq : bk;
        unsigned short* __restrict__ dst = isX ? Qf : Kf;
        bf16x8 xf[8];
#pragma unroll
        for (int ch = 0; ch < 8; ch++)
            xf[ch] = *(const bf16x8*)&X[wg * 16 + low][ch * 32 + q * 8];
        const f32x4 zero = {0.f, 0.f, 0.f, 0.f};
        f32x4 acc[2] = {zero, zero};
#pragma unroll
        for (int rt = 0; rt < 2; rt++)
#pragma unroll
            for (int ch = 0; ch < 8; ch++) {
                uint4 wv = Wf[(rt * 8 + ch) * 64 + lane];
                acc[rt] = __builtin_amdgcn_mfma_f32_16x16x32_bf16(
                    __builtin_bit_cast(bf16x8, wv), xf[ch], acc[rt], 0, 0, 0);
            }
        unsigned short* Pw = &Pl[wg][0];
#pragma unroll
        for (int rt = 0; rt < 2; rt++) {
            float b0 = bias[rt * 16 + q * 4 + 0], b1 = bias[rt * 16 + q * 4 + 1];
            float b2 = bias[rt * 16 + q * 4 + 2], b3 = bias[rt * 16 + q * 4 + 3];
            uint2 pk = {bfpk(acc[rt][0] + b0, acc[rt][1] + b1),
                        bfpk(acc[rt][2] + b2, acc[rt][3] + b3)};
            *(uint2*)(Pw + low * 40 + rt * 16 + q * 4) = pk;
        }
        uint4 frag = *(const uint4*)(Pw + low * 40 + q * 8);
        ((uint4*)dst)[((size_t)b * 256 + pt64 * 4 + wg) * 64 + lane] = frag;
    }

    if (!isX) {
        int mstep = wg >> 1, dh = wg & 1;
        bf16x8 vfr[2][8];
#pragma unroll
        for (int mt = 0; mt < 2; mt++)
#pragma unroll
            for (int ch = 0; ch < 8; ch++)
                vfr[mt][ch] = *(const bf16x8*)&X[mstep * 32 + mt * 16 + low][ch * 32 + q * 8];
        unsigned char* Vv = &Vw[wg][0];
        int msg = pt64 * 2 + mstep;
        const f32x4 zero = {0.f, 0.f, 0.f, 0.f};
#pragma unroll
        for (int dt8 = 0; dt8 < 8; dt8++) {
            int dt = dh * 8 + dt8;
            f32x4 a0 = zero, a1 = zero;
#pragma unroll
            for (int ch = 0; ch < 8; ch++) {
                uint4 wv = Wvf[(dt * 8 + ch) * 64 + lane];
                bf16x8 wfr = __builtin_bit_cast(bf16x8, wv);
                a0 = __builtin_amdgcn_mfma_f32_16x16x32_bf16(vfr[0][ch], wfr, a0, 0, 0, 0);
                a1 = __builtin_amdgcn_mfma_f32_16x16x32_bf16(vfr[1][ch], wfr, a1, 0, 0, 0);
            }
            float bb = bv[dt * 16 + low];
            unsigned w0 = __builtin_amdgcn_cvt_pk_fp8_f32(a0[0] + bb, a0[1] + bb, 0, false);
            w0 = __builtin_amdgcn_cvt_pk_fp8_f32(a0[2] + bb, a0[3] + bb, w0, true);
            unsigned w1 = __builtin_amdgcn_cvt_pk_fp8_f32(a1[0] + bb, a1[1] + bb, 0, false);
            w1 = __builtin_amdgcn_cvt_pk_fp8_f32(a1[2] + bb, a1[3] + bb, w1, true);
            *(unsigned*)(Vv + low * 40 + q * 4) = w0;
            *(unsigned*)(Vv + low * 40 + 16 + q * 4) = w1;
            uint2 fr = *(const uint2*)(Vv + low * 40 + q * 8);
            ((uint2*)Vf)[(((size_t)b * 128 + msg) * 16 + dt) * 64 + lane] = fr;
        }
    }
}

// ---------------------------------------------------------------------------
// Flash attention v10 (full-m, fused output). grid 256 x 512 (1 block/CU).
// Block = (b, g): 64 n rows (4 q-tiles), ALL 4096 m. Waves 0-3: QK^T +
// softmax + P-pack for q-tile = wave (unchanged math). All 8 waves: PV for
// d-slice [wave*32, wave*32+32) via mfma_scale_f32_32x32x64_f8f6f4.
// P fp8 LDS ping-pong as before; V frags global->VGPR, software-pipelined.
// Epilogue: l broadcast via LDS; O -> bf16 LDS transpose (stride 129,
// conflict-free) -> out = gamma*O/l + x, coalesced 256 B rows.
// ---------------------------------------------------------------------------
__global__ __launch_bounds__(512, 2) void attn(
        const unsigned short* __restrict__ Qf, const unsigned short* __restrict__ Kf,
        const unsigned char* __restrict__ Vf, const float* __restrict__ x,
        const float* __restrict__ gamma, float* __restrict__ out) {
    __shared__ __align__(16) unsigned char Pb[2][4][16 * 80];  // 10240 B
    __shared__ float l_sh[64];
    __shared__ unsigned Ot[64 * 129];                          // 33024 B (bf16 pairs)

    // bijective bid swizzle: XCD pair {2b,2b+1} hosts all 64 blocks of b,
    // so each XCD's K+V working set is 1.25 MB (L2-resident).
    int bid = blockIdx.x;
    int xcd = bid & 7, tq = bid >> 3;      // tq in 0..31
    int b = xcd >> 1;
    int g = ((xcd & 1) << 5) + tq;         // 0..63; n0 = g*64

    int wave = threadIdx.x >> 6, lane = threadIdx.x & 63;
    int q = lane >> 4, low = lane & 15;
    int hi = lane >> 5;                    // m-half selector
    int dsel = q & 1;                      // tile-parity selector
    int l31 = lane & 31;
    bool isQK = wave < 4;

    const uint4* Qp = (const uint4*)Qf;
    const uint4* Kp = (const uint4*)Kf + (size_t)b * 256 * 64;
    const uint2* Vq = (const uint2*)(Vf + (size_t)b * 1048576) + (size_t)hi * 1024 + low;
    int dt = wave * 2 + dsel;              // wave's d-tile pair member

    bf16x8 qa;
    if (isQK)
        qa = __builtin_bit_cast(bf16x8, Qp[(size_t)(b * 256 + g * 4 + wave) * 64 + lane]);

    f32x16 acc2[2];                        // [tp]: O^T 32n x 32d tiles
    acc2[0] = (f32x16)(0.f);
    acc2[1] = (f32x16)(0.f);
    float lacc = 0.f;
    const f32x4 zero = {0.f, 0.f, 0.f, 0.f};

    // ---- prologue: S^T(0) -> P(0), prefetch K(1), V(0) frags ----
    uint4 kv[4];
    f32x4 s[4];
    if (isQK) {
#pragma unroll
        for (int u = 0; u < 4; u++)
            kv[u] = Kp[(size_t)u * 64 + lane];
#pragma unroll
        for (int u = 0; u < 4; u++)
            s[u] = __builtin_amdgcn_mfma_f32_16x16x32_bf16(
                __builtin_bit_cast(bf16x8, kv[u]), qa, zero, 0, 0, 0);
#pragma unroll
        for (int u = 0; u < 4; u++)
            kv[u] = Kp[(size_t)(4 + u) * 64 + lane];
        unsigned char* Pw = &Pb[0][wave][0];
#pragma unroll
        for (int u = 0; u < 4; u++) {
            float p0 = __expf(s[u][0] * SCALE_), p1 = __expf(s[u][1] * SCALE_);
            float p2 = __expf(s[u][2] * SCALE_), p3 = __expf(s[u][3] * SCALE_);
            lacc += p0 + p1 + p2 + p3;
            unsigned w = __builtin_amdgcn_cvt_pk_fp8_f32(p0, p1, 0, false);
            w = __builtin_amdgcn_cvt_pk_fp8_f32(p2, p3, w, true);
            *(unsigned*)(Pw + low * 80 + u * 16 + q * 4) = w;
        }
    }
    i32x8 vfc;
    {
        const uint2* Vs = Vq + (size_t)dt * 64;
        long* dqw = (long*)&vfc;
#pragma unroll
        for (int ss = 0; ss < 4; ss++)
            dqw[ss] = *(const long*)(Vs + ss * 16);
    }
    __syncthreads();

    // ---- main loop over 64 m-slabs ----
    for (int i = 0; i < 64; i++) {
        int cur = i & 1, nxt = cur ^ 1;
        bool haveNext = (i + 1 < 64);

        i32x8 vfn;
        if (haveNext) {
            const uint2* Vs = Vq + (size_t)(i + 1) * 2048 + dt * 64;
            long* dqw = (long*)&vfn;
#pragma unroll
            for (int ss = 0; ss < 4; ss++)
                dqw[ss] = *(const long*)(Vs + ss * 16);
        }

        if (isQK && haveNext) {
#pragma unroll
            for (int u = 0; u < 4; u++)
                s[u] = __builtin_amdgcn_mfma_f32_16x16x32_bf16(
                    __builtin_bit_cast(bf16x8, kv[u]), qa, zero, 0, 0, 0);
            if (i + 2 < 64) {
#pragma unroll
                for (int u = 0; u < 4; u++)
                    kv[u] = Kp[(size_t)((i + 2) * 4 + u) * 64 + lane];
            }
        }

        // ---- PV(i): acc2[tp] += V^T P^T (32x32x64, unit scales) ----
        const unsigned char* Pr = &Pb[cur][0][0];
        __builtin_amdgcn_s_setprio(1);
#pragma unroll
        for (int tp = 0; tp < 2; tp++) {
            const unsigned char* pr = Pr + (tp * 2 + dsel) * 1280 + low * 80 + hi * 32;
            i32x8 pf;
            ((uint4*)&pf)[0] = *(const uint4*)pr;
            ((uint4*)&pf)[1] = *(const uint4*)(pr + 16);
            acc2[tp] = __builtin_amdgcn_mfma_scale_f32_32x32x64_f8f6f4(
                vfc, pf, acc2[tp], 0, 0, 0, 127, 0, 127);
        }
        __builtin_amdgcn_s_setprio(0);

        if (isQK && haveNext) {
            unsigned char* Pw = &Pb[nxt][wave][0];
#pragma unroll
            for (int u = 0; u < 4; u++) {
                float p0 = __expf(s[u][0] * SCALE_), p1 = __expf(s[u][1] * SCALE_);
                float p2 = __expf(s[u][2] * SCALE_), p3 = __expf(s[u][3] * SCALE_);
                lacc += p0 + p1 + p2 + p3;
                unsigned w = __builtin_amdgcn_cvt_pk_fp8_f32(p0, p1, 0, false);
                w = __builtin_amdgcn_cvt_pk_fp8_f32(p2, p3, w, true);
                *(unsigned*)(Pw + low * 80 + u * 16 + q * 4) = w;
            }
        }
        if (haveNext) vfc = vfn;
        __syncthreads();
    }

    // ---- l: reduce across quads (full m now), publish per n ----
    if (isQK) {
        lacc += __shfl_xor(lacc, 16, 64);
        lacc += __shfl_xor(lacc, 32, 64);
        if (lane < 16)
            l_sh[wave * 16 + low] = lacc;
    }

    // ---- O^T -> bf16 LDS (row = n, col = d/2; stride 129 == 1 mod 32) ----
    // C layout: n = tp*32 + (lane&31), d = wave*32 + (r&3) + 8*(r>>2) + 4*hi.
#pragma unroll
    for (int tp = 0; tp < 2; tp++)
#pragma unroll
        for (int r = 0; r < 16; r += 2) {
            int col16 = wave * 16 + ((r >> 1) & 1) + 4 * (r >> 2) + 2 * hi;
            Ot[(tp * 32 + l31) * 129 + col16] = bfpk(acc2[tp][r], acc2[tp][r + 1]);
        }
    __syncthreads();

    // ---- out[b][d][n0+lane] = gamma * O/l + x, 256 B coalesced rows ----
    {
        float gm = gamma[0];
        float rinv = gm / l_sh[lane];      // lane == n-within-block
        size_t nb = ((size_t)(b * 256 + wave * 32)) * 4096 + g * 64 + lane;
#pragma unroll 4
        for (int j = 0; j < 32; j++) {
            unsigned pk = Ot[lane * 129 + wave * 16 + (j >> 1)];
            unsigned bits = (j & 1) ? (pk & 0xffff0000u) : (pk << 16);
            float o = __uint_as_float(bits);
            size_t idx = nb + (size_t)j * 4096;
            out[idx] = o * rinv + x[idx];
        }
    }
}

// ---------------------------------------------------------------------------
extern "C" void kernel_launch(void* const* d_in, const int* in_sizes, int n_in,
                              void* d_out, int out_size, void* d_ws, size_t ws_size,
                              hipStream_t stream) {
    const float* x     = (const float*)d_in[0];
    const float* ctx   = (const float*)d_in[1];
    const float* Wq    = (const float*)d_in[2];
    const float* bq    = (const float*)d_in[3];
    const float* Wk    = (const float*)d_in[4];
    const float* bk    = (const float*)d_in[5];
    const float* Wv    = (const float*)d_in[6];
    const float* bv    = (const float*)d_in[7];
    const float* gamma = (const float*)d_in[8];
    float* out = (float*)d_out;

    // ws: Qf 1M | Kf 1M | Vf 4.2M | Wqf/Wkf 16K | Wvf 128K
    unsigned short* Qf = (unsigned short*)d_ws;
    unsigned short* Kf = Qf + (size_t)B_ * N_ * 32;
    unsigned char*  Vf = (unsigned char*)(Kf + (size_t)B_ * M_ * 32);
    uint4* Wqf = (uint4*)(Vf + (size_t)B_ * M_ * C_);
    uint4* Wkf = Wqf + 16 * 64;
    uint4* Wvf = Wkf + 16 * 64;

    prep<<<40, 256, 0, stream>>>(Wq, Wk, Wv, Wqf, Wkf, Wvf);
    fused_proj<<<512, 256, 0, stream>>>(x, ctx, Wqf, Wkf, Wvf, bq, bk, bv, Qf, Kf, Vf);
    attn<<<256, 512, 0, stream>>>(Qf, Kf, Vf, x, gamma, out);
}